// Round 2
// baseline (3178.133 us; speedup 1.0000x reference)
//
#include <hip/hip_runtime.h>

typedef unsigned short u16;
typedef __attribute__((ext_vector_type(8))) __bf16 bf16x8;
typedef __attribute__((ext_vector_type(4))) float f32x4;

constexpr int C = 256;
constexpr int T = 4096;
constexpr int B = 4;
constexpr int NENC = 40;
constexpr int NDEC = 10;
constexpr int TILE = 64;

__device__ __forceinline__ float bf2f(u16 v) {
  union { unsigned u; float f; } x;
  x.u = ((unsigned)v) << 16;
  return x.f;
}
__device__ __forceinline__ u16 f2bf(float f) {
  union { float ff; unsigned u; } x;
  x.ff = f;
  unsigned r = x.u + 0x7fffu + ((x.u >> 16) & 1u);
  return (u16)(r >> 16);
}
// LDS element index with 16B-granule XOR swizzle; row stride = 512 elements (1KB)
__device__ __forceinline__ int swz(int row, int col) {
  return row * 512 + (col ^ ((row & 7) << 3));
}

__global__ void k_cvt(const float* __restrict__ src, u16* __restrict__ dst, int n) {
  int i = blockIdx.x * 256 + threadIdx.x;
  if (i < n) dst[i] = f2bf(src[i]);
}

__global__ void k_zero(float* __restrict__ pooled) {
  int i = blockIdx.x * 256 + threadIdx.x;
  if (i < B * C) pooled[i] = 0.f;
}

__global__ void k_input(const float* __restrict__ x, const float* __restrict__ W,
                        const float* __restrict__ bin, float* __restrict__ h) {
  int idx = blockIdx.x * 256 + threadIdx.x;   // b*C*T + c*T + t
  int t = idx & (T - 1);
  int c = (idx >> 12) & (C - 1);
  int b = idx >> 20;
  float xv = x[b * T + t];
  float xp = (t > 0) ? x[b * T + t - 1] : 0.f;
  h[idx] = W[2 * c] * xp + W[2 * c + 1] * xv + bin[c];
}

// One fused gated residual block.
// grid = 256 (b * 64 t-tiles), block = 512 threads (8 waves, each owns 32 output channels)
__global__ __launch_bounds__(512, 2) void k_enc(
    const float* __restrict__ hin, float* __restrict__ hout, float* __restrict__ pooled,
    const u16* __restrict__ Wf, const float* __restrict__ bfb,
    const u16* __restrict__ Wg, const float* __restrict__ bgb,
    const u16* __restrict__ Wr, const float* __restrict__ brb,
    const u16* __restrict__ Ws, const float* __restrict__ bsb,
    int dil) {
  __shared__ __align__(16) u16 lds[64 * 512];   // 64KB: B1 [n=64][k=512], later B2 [n=64][k=256]
  const int tid = threadIdx.x;
  const int wave = tid >> 6;
  const int lane = tid & 63;
  const int ncol = lane & 15;
  const int quad = lane >> 4;
  const int wg = blockIdx.x;
  const int b = wg >> 6;
  const int t0 = (wg & 63) * TILE;
  const float* hb = hin + b * C * T;

  // ---- stage B1: lds[n][2*ci+tap] = bf16(h[b][ci][t0+n - (tap?dil:0)]) ----
  for (int s = tid; s < 2 * C * TILE; s += 512) {
    int n = s & 63;
    int ci = (s >> 6) & 255;
    int tap = s >> 14;                   // 0 = past tap (t-dil), 1 = current
    int t = t0 + n - (tap ? 0 : dil);
    float v = (t >= 0) ? hb[ci * T + t] : 0.f;
    lds[swz(n, 2 * ci + tap)] = f2bf(v);
  }
  __syncthreads();

  // ---- phase 1: [f;g] = W_fg @ B1,  M=512 K=512 N=64 ----
  const int co0 = wave * 32;
  const int mrow = lane & 15;
  const int kq = quad * 8;
  const u16* ar0 = Wf + (co0 + mrow) * 512;
  const u16* ar1 = Wf + (co0 + 16 + mrow) * 512;
  const u16* ar2 = Wg + (co0 + mrow) * 512;
  const u16* ar3 = Wg + (co0 + 16 + mrow) * 512;

  f32x4 acc[4][4];
#pragma unroll
  for (int m = 0; m < 4; ++m)
#pragma unroll
    for (int nt = 0; nt < 4; ++nt)
      acc[m][nt] = (f32x4){0.f, 0.f, 0.f, 0.f};

  for (int it = 0; it < 16; ++it) {
    const int kk = it * 32 + kq;
    bf16x8 a0 = *(const bf16x8*)(ar0 + kk);
    bf16x8 a1 = *(const bf16x8*)(ar1 + kk);
    bf16x8 a2 = *(const bf16x8*)(ar2 + kk);
    bf16x8 a3 = *(const bf16x8*)(ar3 + kk);
    bf16x8 bfr[4];
#pragma unroll
    for (int nt = 0; nt < 4; ++nt)
      bfr[nt] = *(const bf16x8*)(&lds[swz(nt * 16 + ncol, kk)]);
#pragma unroll
    for (int nt = 0; nt < 4; ++nt) {
      acc[0][nt] = __builtin_amdgcn_mfma_f32_16x16x32_bf16(a0, bfr[nt], acc[0][nt], 0, 0, 0);
      acc[1][nt] = __builtin_amdgcn_mfma_f32_16x16x32_bf16(a1, bfr[nt], acc[1][nt], 0, 0, 0);
      acc[2][nt] = __builtin_amdgcn_mfma_f32_16x16x32_bf16(a2, bfr[nt], acc[2][nt], 0, 0, 0);
      acc[3][nt] = __builtin_amdgcn_mfma_f32_16x16x32_bf16(a3, bfr[nt], acc[3][nt], 0, 0, 0);
    }
  }
  __syncthreads();   // all waves done reading B1

  // ---- gating: out = tanh(f+bf) * sigmoid(g+bg) -> LDS as B2[k=co][n] ----
#pragma unroll
  for (int j = 0; j < 2; ++j) {
    const int cob = co0 + j * 16 + quad * 4;
    float bfv[4], bgv[4];
#pragma unroll
    for (int r = 0; r < 4; ++r) {
      bfv[r] = bfb[cob + r];
      bgv[r] = bgb[cob + r];
    }
#pragma unroll
    for (int nt = 0; nt < 4; ++nt) {
      const int n = nt * 16 + ncol;
      u16 pk[4];
#pragma unroll
      for (int r = 0; r < 4; ++r) {
        float fv = acc[j][nt][r] + bfv[r];
        float gv = acc[2 + j][nt][r] + bgv[r];
        float th = 1.f - 2.f / (__expf(2.f * fv) + 1.f);
        float sg = 1.f / (1.f + __expf(-gv));
        pk[r] = f2bf(th * sg);
      }
      uint2 w;
      w.x = (unsigned)pk[0] | ((unsigned)pk[1] << 16);
      w.y = (unsigned)pk[2] | ((unsigned)pk[3] << 16);
      *(uint2*)(&lds[swz(n, cob)]) = w;
    }
  }
  __syncthreads();

  // ---- phase 2: [res;skip] = W_rs @ out,  M=512 K=256 N=64 ----
  const u16* rr0 = Wr + (co0 + mrow) * 256;
  const u16* rr1 = Wr + (co0 + 16 + mrow) * 256;
  const u16* rr2 = Ws + (co0 + mrow) * 256;
  const u16* rr3 = Ws + (co0 + 16 + mrow) * 256;
  f32x4 acc2[4][4];
#pragma unroll
  for (int m = 0; m < 4; ++m)
#pragma unroll
    for (int nt = 0; nt < 4; ++nt)
      acc2[m][nt] = (f32x4){0.f, 0.f, 0.f, 0.f};

  for (int it = 0; it < 8; ++it) {
    const int kk = it * 32 + kq;
    bf16x8 a0 = *(const bf16x8*)(rr0 + kk);
    bf16x8 a1 = *(const bf16x8*)(rr1 + kk);
    bf16x8 a2 = *(const bf16x8*)(rr2 + kk);
    bf16x8 a3 = *(const bf16x8*)(rr3 + kk);
    bf16x8 bfr[4];
#pragma unroll
    for (int nt = 0; nt < 4; ++nt)
      bfr[nt] = *(const bf16x8*)(&lds[swz(nt * 16 + ncol, kk)]);
#pragma unroll
    for (int nt = 0; nt < 4; ++nt) {
      acc2[0][nt] = __builtin_amdgcn_mfma_f32_16x16x32_bf16(a0, bfr[nt], acc2[0][nt], 0, 0, 0);
      acc2[1][nt] = __builtin_amdgcn_mfma_f32_16x16x32_bf16(a1, bfr[nt], acc2[1][nt], 0, 0, 0);
      acc2[2][nt] = __builtin_amdgcn_mfma_f32_16x16x32_bf16(a2, bfr[nt], acc2[2][nt], 0, 0, 0);
      acc2[3][nt] = __builtin_amdgcn_mfma_f32_16x16x32_bf16(a3, bfr[nt], acc2[3][nt], 0, 0, 0);
    }
  }

  // ---- epilogue: residual write (f32) + skip t-reduction into pooled ----
  float* ho = hout + b * C * T;
#pragma unroll
  for (int m = 0; m < 2; ++m) {
    const int cob = co0 + m * 16 + quad * 4;
#pragma unroll
    for (int nt = 0; nt < 4; ++nt) {
      const int t = t0 + nt * 16 + ncol;
#pragma unroll
      for (int r = 0; r < 4; ++r) {
        const int co = cob + r;
        ho[co * T + t] = acc2[m][nt][r] + brb[co] + hb[co * T + t];
      }
    }
  }
  float* pb = pooled + b * C;
#pragma unroll
  for (int m = 0; m < 2; ++m) {
    const int cob = co0 + m * 16 + quad * 4;
#pragma unroll
    for (int r = 0; r < 4; ++r) {
      float s = acc2[2 + m][0][r] + acc2[2 + m][1][r] + acc2[2 + m][2][r] + acc2[2 + m][3][r];
      s += __shfl_xor(s, 1);
      s += __shfl_xor(s, 2);
      s += __shfl_xor(s, 4);
      s += __shfl_xor(s, 8);
      if (ncol == 0) atomicAdd(&pb[cob + r], s + 64.f * bsb[cob + r]);
    }
  }
}

__global__ __launch_bounds__(256) void k_fc(
    const float* __restrict__ pooled,
    const float* __restrict__ muW, const float* __restrict__ mub,
    const float* __restrict__ lvW, const float* __restrict__ lvb,
    const float* __restrict__ eps, float* __restrict__ zbuf,
    float* __restrict__ dout) {
  __shared__ float pm[B * C];
  const int tid = threadIdx.x;
  for (int i = tid; i < B * C; i += 256) pm[i] = pooled[i] * (1.f / (float)T);
  __syncthreads();
  if (tid < 128) {
    const int l = tid;
    for (int b = 0; b < B; ++b) {
      float mu = mub[l];
      float lv = lvb[l];
      const float* p = pm + b * C;
      for (int c = 0; c < C; ++c) {
        float pv = p[c];
        mu += pv * muW[l * C + c];
        lv += pv * lvW[l * C + c];
      }
      float z = mu + eps[b * 128 + l] * expf(0.5f * lv);
      zbuf[b * 128 + l] = z;
      dout[4 + b * 128 + l] = mu;
      dout[4 + 512 + b * 128 + l] = lv;
    }
  }
}

// Decoder on length-1 sequence: causal conv k=2 collapses to tap-1 matvec.
__global__ __launch_bounds__(256) void k_dec(
    const float* __restrict__ zbuf,
    const float* __restrict__ dinW, const float* __restrict__ dinb,
    const float* __restrict__ dWf, const float* __restrict__ dbf,
    const float* __restrict__ dWg, const float* __restrict__ dbg,
    const float* __restrict__ dWr, const float* __restrict__ dbr,
    const float* __restrict__ outW, const float* __restrict__ outb,
    float* __restrict__ dout) {
  __shared__ float h2[C], og[C], zs[128], red[256];
  const int b = blockIdx.x;
  const int c = threadIdx.x;
  if (c < 128) zs[c] = zbuf[b * 128 + c];
  __syncthreads();
  float a = dinb[c];
  for (int l = 0; l < 128; ++l) a += dinW[c * 128 + l] * zs[l];
  h2[c] = a;
  __syncthreads();
  for (int i = 0; i < NDEC; ++i) {
    const float* wf = dWf + (size_t)(i * C + c) * C * 2;
    const float* wg = dWg + (size_t)(i * C + c) * C * 2;
    float f = dbf[i * C + c];
    float g = dbg[i * C + c];
    for (int ci = 0; ci < C; ++ci) {
      float hv = h2[ci];
      f += wf[2 * ci + 1] * hv;   // tap 1 only (tap 0 hits the causal pad = 0)
      g += wg[2 * ci + 1] * hv;
    }
    float o = (1.f - 2.f / (__expf(2.f * f) + 1.f)) * (1.f / (1.f + __expf(-g)));
    og[c] = o;
    __syncthreads();
    const float* wr = dWr + (size_t)(i * C + c) * C;
    float r = dbr[i * C + c];
    for (int ci = 0; ci < C; ++ci) r += wr[ci] * og[ci];
    __syncthreads();
    h2[c] += r;
    __syncthreads();
  }
  red[c] = outW[c] * h2[c];
  __syncthreads();
  for (int st = 128; st > 0; st >>= 1) {
    if (c < st) red[c] += red[c + st];
    __syncthreads();
  }
  if (c == 0) dout[b] = red[0] + outb[0];
}

extern "C" void kernel_launch(void* const* d_in, const int* in_sizes, int n_in,
                              void* d_out, int out_size, void* d_ws, size_t ws_size,
                              hipStream_t stream) {
  const float* x      = (const float*)d_in[0];
  const float* eps    = (const float*)d_in[1];
  const float* encinW = (const float*)d_in[2];
  const float* encinb = (const float*)d_in[3];
  const float* encWf  = (const float*)d_in[4];
  const float* encbf  = (const float*)d_in[5];
  const float* encWg  = (const float*)d_in[6];
  const float* encbg  = (const float*)d_in[7];
  const float* encWr  = (const float*)d_in[8];
  const float* encbr  = (const float*)d_in[9];
  const float* encWs  = (const float*)d_in[10];
  const float* encbs  = (const float*)d_in[11];
  const float* muW    = (const float*)d_in[12];
  const float* mub    = (const float*)d_in[13];
  const float* lvW    = (const float*)d_in[14];
  const float* lvb    = (const float*)d_in[15];
  const float* dinW   = (const float*)d_in[16];
  const float* dinb   = (const float*)d_in[17];
  const float* dWf    = (const float*)d_in[18];
  const float* dbf    = (const float*)d_in[19];
  const float* dWg    = (const float*)d_in[20];
  const float* dbg    = (const float*)d_in[21];
  const float* dWr    = (const float*)d_in[22];
  const float* dbr    = (const float*)d_in[23];
  const float* outW   = (const float*)d_in[24];
  const float* outb   = (const float*)d_in[25];
  float* dout = (float*)d_out;

  char* ws = (char*)d_ws;
  float* hA = (float*)ws;                              // [4][256][4096] f32 = 16 MB
  float* hB = hA + (size_t)B * C * T;                  // ping-pong, 16 MB
  float* pooled = hB + (size_t)B * C * T;              // [4][256] f32
  float* zbuf = pooled + B * C;                        // [4][128] f32
  u16* wWf = (u16*)(zbuf + B * 128);                   // [40][256][512] bf16
  u16* wWg = wWf + (size_t)NENC * C * C * 2;
  u16* wWr = wWg + (size_t)NENC * C * C * 2;           // [40][256][256] bf16
  u16* wWs = wWr + (size_t)NENC * C * C;

  const int nFG = NENC * C * C * 2;   // 5,242,880
  const int nRS = NENC * C * C;       // 2,621,440
  k_cvt<<<(nFG + 255) / 256, 256, 0, stream>>>(encWf, wWf, nFG);
  k_cvt<<<(nFG + 255) / 256, 256, 0, stream>>>(encWg, wWg, nFG);
  k_cvt<<<(nRS + 255) / 256, 256, 0, stream>>>(encWr, wWr, nRS);
  k_cvt<<<(nRS + 255) / 256, 256, 0, stream>>>(encWs, wWs, nRS);

  k_zero<<<4, 256, 0, stream>>>(pooled);
  k_input<<<(B * C * T) / 256, 256, 0, stream>>>(x, encinW, encinb, hA);

  for (int i = 0; i < NENC; ++i) {
    const int dil = 1 << (i % 10);
    const float* hi = (i & 1) ? hB : hA;
    float* ho = (i & 1) ? hA : hB;
    k_enc<<<256, 512, 0, stream>>>(
        hi, ho, pooled,
        wWf + (size_t)i * C * C * 2, encbf + (size_t)i * C,
        wWg + (size_t)i * C * C * 2, encbg + (size_t)i * C,
        wWr + (size_t)i * C * C,     encbr + (size_t)i * C,
        wWs + (size_t)i * C * C,     encbs + (size_t)i * C,
        dil);
  }

  k_fc<<<1, 256, 0, stream>>>(pooled, muW, mub, lvW, lvb, eps, zbuf, dout);
  k_dec<<<B, 256, 0, stream>>>(zbuf, dinW, dinb, dWf, dbf, dWg, dbg, dWr, dbr,
                               outW, outb, dout);
}

// Round 3
// 2091.956 us; speedup vs baseline: 1.5192x; 1.5192x over previous
//
#include <hip/hip_runtime.h>

typedef unsigned short u16;
typedef __attribute__((ext_vector_type(8))) __bf16 bf16x8;
typedef __attribute__((ext_vector_type(4))) float f32x4;

constexpr int C = 256;
constexpr int T = 4096;
constexpr int B = 4;
constexpr int NENC = 40;
constexpr int NDEC = 10;
constexpr int TILE = 64;

__device__ __forceinline__ float bf2f(u16 v) {
  union { unsigned u; float f; } x;
  x.u = ((unsigned)v) << 16;
  return x.f;
}
__device__ __forceinline__ u16 f2bf(float f) {
  union { float ff; unsigned u; } x;
  x.ff = f;
  unsigned r = x.u + 0x7fffu + ((x.u >> 16) & 1u);
  return (u16)(r >> 16);
}
// LDS elem index; row stride 512 elems (1KB). 16B-granule XOR swizzle with
// (row&7)^(row>>3): b128 frag reads stay <=2-way (free), staging b16 writes
// spread across all 32 banks (was 8-way with row&7 only).
__device__ __forceinline__ int swz(int row, int col) {
  int g = ((row & 7) ^ (row >> 3)) & 7;
  return row * 512 + (col ^ (g << 3));
}

__global__ void k_cvt(const float* __restrict__ src, u16* __restrict__ dst, int n) {
  int i = blockIdx.x * 256 + threadIdx.x;
  if (i < n) dst[i] = f2bf(src[i]);
}

__global__ void k_zero(float* __restrict__ pooled) {
  int i = blockIdx.x * 256 + threadIdx.x;
  if (i < B * C) pooled[i] = 0.f;
}

// transpose decoder weights: tW*[layer][ci][c] (bf16, tap-1 only for f/g)
__global__ void k_tdec(const float* __restrict__ dWf, const float* __restrict__ dWg,
                       const float* __restrict__ dWr, const float* __restrict__ dinW,
                       u16* __restrict__ tWf, u16* __restrict__ tWg,
                       u16* __restrict__ tWr, float* __restrict__ tdin) {
  int i = blockIdx.x * 256 + threadIdx.x;
  if (i < NDEC * C * C) {
    int layer = i >> 16;
    int rem = i & 65535;
    int ci = rem >> 8;
    int c = rem & 255;
    size_t src = ((size_t)(layer * C + c) * C + ci);
    tWf[i] = f2bf(dWf[src * 2 + 1]);
    tWg[i] = f2bf(dWg[src * 2 + 1]);
    tWr[i] = f2bf(dWr[src]);
  }
  if (i < 128 * C) {
    int l = i >> 8;
    int c = i & 255;
    tdin[i] = dinW[c * 128 + l];
  }
}

__global__ void k_input(const float* __restrict__ x, const float* __restrict__ W,
                        const float* __restrict__ bin, float* __restrict__ h) {
  int idx = blockIdx.x * 256 + threadIdx.x;
  int t = idx & (T - 1);
  int c = (idx >> 12) & (C - 1);
  int b = idx >> 20;
  float xv = x[b * T + t];
  float xp = (t > 0) ? x[b * T + t - 1] : 0.f;
  h[idx] = W[2 * c] * xp + W[2 * c + 1] * xv + bin[c];
}

// One fused gated residual block. grid=256 (b x 64 t-tiles), block=512 (8 waves x 32 co)
__global__ __launch_bounds__(512, 2) void k_enc(
    const float* __restrict__ hin, float* __restrict__ hout, float* __restrict__ pooled,
    const u16* __restrict__ Wf, const float* __restrict__ bfb,
    const u16* __restrict__ Wg, const float* __restrict__ bgb,
    const u16* __restrict__ Wr, const float* __restrict__ brb,
    const u16* __restrict__ Ws, const float* __restrict__ bsb,
    int dil) {
  __shared__ __align__(16) u16 lds[64 * 512];
  const int tid = threadIdx.x;
  const int wave = tid >> 6;
  const int lane = tid & 63;
  const int ncol = lane & 15;
  const int quad = lane >> 4;
  const int wg = blockIdx.x;
  const int b = wg >> 6;
  const int t0 = (wg & 63) * TILE;
  const float* hb = hin + b * C * T;

  // ---- stage B1: lds[n][2ci+tap] = bf16(h[ci][t0+n-(tap?0:dil)]) ----
  // thread -> (n4 = tid&15 [covers n=4*n4..+3], ci = (tid>>4)+it2*32, tap = it2>>3)
  const int n4 = tid & 15;
  const int cib = tid >> 4;
  float4 v[16];
  const bool fast0 = ((dil & 3) == 0) && (t0 >= dil);
  if (fast0) {
#pragma unroll
    for (int it2 = 0; it2 < 16; ++it2) {
      int ci = (cib + it2 * 32) & 255;
      int tap = it2 >> 3;
      int tb = t0 + n4 * 4 - (tap ? 0 : dil);
      v[it2] = *(const float4*)(hb + ci * T + tb);
    }
  } else {
#pragma unroll
    for (int it2 = 0; it2 < 16; ++it2) {
      int ci = (cib + it2 * 32) & 255;
      int tap = it2 >> 3;
      int tb = t0 + n4 * 4 - (tap ? 0 : dil);
      const float* p = hb + ci * T + tb;
      if (tap) {
        v[it2] = *(const float4*)p;
      } else {
        v[it2].x = (tb + 0 >= 0) ? p[0] : 0.f;
        v[it2].y = (tb + 1 >= 0) ? p[1] : 0.f;
        v[it2].z = (tb + 2 >= 0) ? p[2] : 0.f;
        v[it2].w = (tb + 3 >= 0) ? p[3] : 0.f;
      }
    }
  }
#pragma unroll
  for (int it2 = 0; it2 < 16; ++it2) {
    int ci = (cib + it2 * 32) & 255;
    int tap = it2 >> 3;
    int col = 2 * ci + tap;
    lds[swz(n4 * 4 + 0, col)] = f2bf(v[it2].x);
    lds[swz(n4 * 4 + 1, col)] = f2bf(v[it2].y);
    lds[swz(n4 * 4 + 2, col)] = f2bf(v[it2].z);
    lds[swz(n4 * 4 + 3, col)] = f2bf(v[it2].w);
  }
  __syncthreads();

  // ---- phase 1: [f;g] = W_fg @ B1,  M=512 K=512 N=64 ----
  const int co0 = wave * 32;
  const int mrow = lane & 15;
  const int kq = quad * 8;
  const u16* ar0 = Wf + (co0 + mrow) * 512;
  const u16* ar1 = Wf + (co0 + 16 + mrow) * 512;
  const u16* ar2 = Wg + (co0 + mrow) * 512;
  const u16* ar3 = Wg + (co0 + 16 + mrow) * 512;

  f32x4 acc[4][4];
#pragma unroll
  for (int m = 0; m < 4; ++m)
#pragma unroll
    for (int nt = 0; nt < 4; ++nt)
      acc[m][nt] = (f32x4){0.f, 0.f, 0.f, 0.f};

#pragma unroll
  for (int it = 0; it < 16; ++it) {
    const int kk = it * 32 + kq;
    bf16x8 a0 = *(const bf16x8*)(ar0 + kk);
    bf16x8 a1 = *(const bf16x8*)(ar1 + kk);
    bf16x8 a2 = *(const bf16x8*)(ar2 + kk);
    bf16x8 a3 = *(const bf16x8*)(ar3 + kk);
    bf16x8 bfr[4];
#pragma unroll
    for (int nt = 0; nt < 4; ++nt)
      bfr[nt] = *(const bf16x8*)(&lds[swz(nt * 16 + ncol, kk)]);
#pragma unroll
    for (int nt = 0; nt < 4; ++nt) {
      acc[0][nt] = __builtin_amdgcn_mfma_f32_16x16x32_bf16(a0, bfr[nt], acc[0][nt], 0, 0, 0);
      acc[1][nt] = __builtin_amdgcn_mfma_f32_16x16x32_bf16(a1, bfr[nt], acc[1][nt], 0, 0, 0);
      acc[2][nt] = __builtin_amdgcn_mfma_f32_16x16x32_bf16(a2, bfr[nt], acc[2][nt], 0, 0, 0);
      acc[3][nt] = __builtin_amdgcn_mfma_f32_16x16x32_bf16(a3, bfr[nt], acc[3][nt], 0, 0, 0);
    }
  }
  __syncthreads();

  // ---- gating -> LDS as B2[k=co][n] ----
#pragma unroll
  for (int j = 0; j < 2; ++j) {
    const int cob = co0 + j * 16 + quad * 4;
    float bfv[4], bgv[4];
#pragma unroll
    for (int r = 0; r < 4; ++r) {
      bfv[r] = bfb[cob + r];
      bgv[r] = bgb[cob + r];
    }
#pragma unroll
    for (int nt = 0; nt < 4; ++nt) {
      const int n = nt * 16 + ncol;
      u16 pk[4];
#pragma unroll
      for (int r = 0; r < 4; ++r) {
        float fv = acc[j][nt][r] + bfv[r];
        float gv = acc[2 + j][nt][r] + bgv[r];
        float th = 1.f - 2.f / (__expf(2.f * fv) + 1.f);
        float sg = 1.f / (1.f + __expf(-gv));
        pk[r] = f2bf(th * sg);
      }
      uint2 w;
      w.x = (unsigned)pk[0] | ((unsigned)pk[1] << 16);
      w.y = (unsigned)pk[2] | ((unsigned)pk[3] << 16);
      *(uint2*)(&lds[swz(n, cob)]) = w;
    }
  }
  __syncthreads();

  // ---- phase 2: [res;skip] = W_rs @ out,  M=512 K=256 N=64 ----
  const u16* rr0 = Wr + (co0 + mrow) * 256;
  const u16* rr1 = Wr + (co0 + 16 + mrow) * 256;
  const u16* rr2 = Ws + (co0 + mrow) * 256;
  const u16* rr3 = Ws + (co0 + 16 + mrow) * 256;
  f32x4 acc2[4][4];
#pragma unroll
  for (int m = 0; m < 4; ++m)
#pragma unroll
    for (int nt = 0; nt < 4; ++nt)
      acc2[m][nt] = (f32x4){0.f, 0.f, 0.f, 0.f};

#pragma unroll
  for (int it = 0; it < 8; ++it) {
    const int kk = it * 32 + kq;
    bf16x8 a0 = *(const bf16x8*)(rr0 + kk);
    bf16x8 a1 = *(const bf16x8*)(rr1 + kk);
    bf16x8 a2 = *(const bf16x8*)(rr2 + kk);
    bf16x8 a3 = *(const bf16x8*)(rr3 + kk);
    bf16x8 bfr[4];
#pragma unroll
    for (int nt = 0; nt < 4; ++nt)
      bfr[nt] = *(const bf16x8*)(&lds[swz(nt * 16 + ncol, kk)]);
#pragma unroll
    for (int nt = 0; nt < 4; ++nt) {
      acc2[0][nt] = __builtin_amdgcn_mfma_f32_16x16x32_bf16(a0, bfr[nt], acc2[0][nt], 0, 0, 0);
      acc2[1][nt] = __builtin_amdgcn_mfma_f32_16x16x32_bf16(a1, bfr[nt], acc2[1][nt], 0, 0, 0);
      acc2[2][nt] = __builtin_amdgcn_mfma_f32_16x16x32_bf16(a2, bfr[nt], acc2[2][nt], 0, 0, 0);
      acc2[3][nt] = __builtin_amdgcn_mfma_f32_16x16x32_bf16(a3, bfr[nt], acc2[3][nt], 0, 0, 0);
    }
  }

  // ---- epilogue: residual write (f32) + skip reduce into pooled ----
  float hold[32];
  float brv[2][4];
#pragma unroll
  for (int m = 0; m < 2; ++m)
#pragma unroll
    for (int r = 0; r < 4; ++r)
      brv[m][r] = brb[co0 + m * 16 + quad * 4 + r];
#pragma unroll
  for (int m = 0; m < 2; ++m)
#pragma unroll
    for (int nt = 0; nt < 4; ++nt)
#pragma unroll
      for (int r = 0; r < 4; ++r)
        hold[(m * 4 + nt) * 4 + r] =
            hb[(co0 + m * 16 + quad * 4 + r) * T + (t0 + nt * 16 + ncol)];

  float* ho = hout + b * C * T;
#pragma unroll
  for (int m = 0; m < 2; ++m)
#pragma unroll
    for (int nt = 0; nt < 4; ++nt)
#pragma unroll
      for (int r = 0; r < 4; ++r)
        ho[(co0 + m * 16 + quad * 4 + r) * T + (t0 + nt * 16 + ncol)] =
            acc2[m][nt][r] + brv[m][r] + hold[(m * 4 + nt) * 4 + r];

  float* pb = pooled + b * C;
#pragma unroll
  for (int m = 0; m < 2; ++m) {
    const int cob = co0 + m * 16 + quad * 4;
#pragma unroll
    for (int r = 0; r < 4; ++r) {
      float s = acc2[2 + m][0][r] + acc2[2 + m][1][r] + acc2[2 + m][2][r] + acc2[2 + m][3][r];
      s += __shfl_xor(s, 1);
      s += __shfl_xor(s, 2);
      s += __shfl_xor(s, 4);
      s += __shfl_xor(s, 8);
      if (ncol == 0) atomicAdd(&pb[cob + r], s + 64.f * bsb[cob + r]);
    }
  }
}

// wave-per-dot FC: 1024 dots (b x {mu,lv} x 128), K=256. grid=16 x 256.
__global__ __launch_bounds__(256) void k_fc(
    const float* __restrict__ pooled,
    const float* __restrict__ muW, const float* __restrict__ mub,
    const float* __restrict__ lvW, const float* __restrict__ lvb,
    float* __restrict__ mlbuf, float* __restrict__ dout) {
  __shared__ float pm[B * C];
  const int tid = threadIdx.x;
  for (int i = tid; i < B * C; i += 256) pm[i] = pooled[i] * (1.f / (float)T);
  __syncthreads();
  const int waveG = blockIdx.x * 4 + (tid >> 6);
  const int lane = tid & 63;
  for (int j = 0; j < 16; ++j) {
    int d = waveG * 16 + j;
    int b = d >> 8, r = d & 255, which = r >> 7, l = r & 127;
    const float* Wrow = (which ? lvW : muW) + l * C;
    const float* p = pm + b * C;
    float s = Wrow[lane] * p[lane] + Wrow[lane + 64] * p[lane + 64] +
              Wrow[lane + 128] * p[lane + 128] + Wrow[lane + 192] * p[lane + 192];
#pragma unroll
    for (int off = 32; off; off >>= 1) s += __shfl_xor(s, off);
    if (lane == 0) {
      float val = s + (which ? lvb[l] : mub[l]);
      mlbuf[which * 512 + b * 128 + l] = val;
      dout[4 + which * 512 + b * 128 + l] = val;
    }
  }
}

// Decoder (T=1): transposed bf16 weights, coalesced across threads.
__global__ __launch_bounds__(256) void k_dec(
    const float* __restrict__ mlbuf, const float* __restrict__ eps,
    const float* __restrict__ tdin, const float* __restrict__ dinb,
    const u16* __restrict__ tWf, const float* __restrict__ dbf,
    const u16* __restrict__ tWg, const float* __restrict__ dbg,
    const u16* __restrict__ tWr, const float* __restrict__ dbr,
    const float* __restrict__ outW, const float* __restrict__ outb,
    float* __restrict__ dout) {
  __shared__ float h2s[C], og[C], zs[128], red[256];
  const int b = blockIdx.x;
  const int c = threadIdx.x;
  if (c < 128) {
    float mu = mlbuf[b * 128 + c];
    float lv = mlbuf[512 + b * 128 + c];
    zs[c] = mu + eps[b * 128 + c] * expf(0.5f * lv);
  }
  __syncthreads();
  float h2 = dinb[c];
#pragma unroll 8
  for (int l = 0; l < 128; ++l) h2 += tdin[l * 256 + c] * zs[l];
  h2s[c] = h2;
  __syncthreads();
  for (int i = 0; i < NDEC; ++i) {
    const u16* wf = tWf + i * 65536;
    const u16* wg = tWg + i * 65536;
    const u16* wr = tWr + i * 65536;
    float f = dbf[i * C + c];
    float g = dbg[i * C + c];
#pragma unroll 8
    for (int ci = 0; ci < C; ++ci) {
      float hv = h2s[ci];
      f += bf2f(wf[ci * 256 + c]) * hv;
      g += bf2f(wg[ci * 256 + c]) * hv;
    }
    float o = (1.f - 2.f / (__expf(2.f * f) + 1.f)) * (1.f / (1.f + __expf(-g)));
    og[c] = o;
    __syncthreads();
    float r = dbr[i * C + c];
#pragma unroll 8
    for (int ci = 0; ci < C; ++ci) r += bf2f(wr[ci * 256 + c]) * og[ci];
    __syncthreads();
    h2 += r;
    h2s[c] = h2;
    __syncthreads();
  }
  red[c] = outW[c] * h2;
  __syncthreads();
  for (int st = 128; st > 0; st >>= 1) {
    if (c < st) red[c] += red[c + st];
    __syncthreads();
  }
  if (c == 0) dout[b] = red[0] + outb[0];
}

extern "C" void kernel_launch(void* const* d_in, const int* in_sizes, int n_in,
                              void* d_out, int out_size, void* d_ws, size_t ws_size,
                              hipStream_t stream) {
  const float* x      = (const float*)d_in[0];
  const float* eps    = (const float*)d_in[1];
  const float* encinW = (const float*)d_in[2];
  const float* encinb = (const float*)d_in[3];
  const float* encWf  = (const float*)d_in[4];
  const float* encbf  = (const float*)d_in[5];
  const float* encWg  = (const float*)d_in[6];
  const float* encbg  = (const float*)d_in[7];
  const float* encWr  = (const float*)d_in[8];
  const float* encbr  = (const float*)d_in[9];
  const float* encWs  = (const float*)d_in[10];
  const float* encbs  = (const float*)d_in[11];
  const float* muW    = (const float*)d_in[12];
  const float* mub    = (const float*)d_in[13];
  const float* lvW    = (const float*)d_in[14];
  const float* lvb    = (const float*)d_in[15];
  const float* dinW   = (const float*)d_in[16];
  const float* dinb   = (const float*)d_in[17];
  const float* dWf    = (const float*)d_in[18];
  const float* dbf    = (const float*)d_in[19];
  const float* dWg    = (const float*)d_in[20];
  const float* dbg    = (const float*)d_in[21];
  const float* dWr    = (const float*)d_in[22];
  const float* dbr    = (const float*)d_in[23];
  const float* outW   = (const float*)d_in[24];
  const float* outb   = (const float*)d_in[25];
  float* dout = (float*)d_out;

  const int nFG = NENC * C * C * 2;
  const int nRS = NENC * C * C;
  const int nTD = NDEC * C * C;

  char* ws = (char*)d_ws;
  float* hA = (float*)ws;
  float* hB = hA + (size_t)B * C * T;
  float* pooled = hB + (size_t)B * C * T;
  float* mlbuf = pooled + B * C;
  float* tdin = mlbuf + 1024;
  u16* wWf = (u16*)(tdin + 128 * C);
  u16* wWg = wWf + (size_t)nFG;
  u16* wWr = wWg + (size_t)nFG;
  u16* wWs = wWr + (size_t)nRS;
  u16* tWf = wWs + (size_t)nRS;
  u16* tWg = tWf + (size_t)nTD;
  u16* tWr = tWg + (size_t)nTD;

  k_cvt<<<(nFG + 255) / 256, 256, 0, stream>>>(encWf, wWf, nFG);
  k_cvt<<<(nFG + 255) / 256, 256, 0, stream>>>(encWg, wWg, nFG);
  k_cvt<<<(nRS + 255) / 256, 256, 0, stream>>>(encWr, wWr, nRS);
  k_cvt<<<(nRS + 255) / 256, 256, 0, stream>>>(encWs, wWs, nRS);
  k_tdec<<<(nTD + 255) / 256, 256, 0, stream>>>(dWf, dWg, dWr, dinW, tWf, tWg, tWr, tdin);

  k_zero<<<4, 256, 0, stream>>>(pooled);
  k_input<<<(B * C * T) / 256, 256, 0, stream>>>(x, encinW, encinb, hA);

  for (int i = 0; i < NENC; ++i) {
    const int dil = 1 << (i % 10);
    const float* hi = (i & 1) ? hB : hA;
    float* ho = (i & 1) ? hA : hB;
    k_enc<<<256, 512, 0, stream>>>(
        hi, ho, pooled,
        wWf + (size_t)i * C * C * 2, encbf + (size_t)i * C,
        wWg + (size_t)i * C * C * 2, encbg + (size_t)i * C,
        wWr + (size_t)i * C * C,     encbr + (size_t)i * C,
        wWs + (size_t)i * C * C,     encbs + (size_t)i * C,
        dil);
  }

  k_fc<<<16, 256, 0, stream>>>(pooled, muW, mub, lvW, lvb, mlbuf, dout);
  k_dec<<<B, 256, 0, stream>>>(mlbuf, eps, tdin, dinb, tWf, dbf, tWg, dbg,
                               tWr, dbr, outW, outb, dout);
}

// Round 4
// 2003.497 us; speedup vs baseline: 1.5863x; 1.0442x over previous
//
#include <hip/hip_runtime.h>

typedef unsigned short u16;
typedef __attribute__((ext_vector_type(8))) __bf16 bf16x8;
typedef __attribute__((ext_vector_type(4))) float f32x4;

constexpr int C = 256;
constexpr int T = 4096;
constexpr int B = 4;
constexpr int NENC = 40;
constexpr int NDEC = 10;
constexpr int TILE = 64;

__device__ __forceinline__ float bf2f(u16 v) {
  union { unsigned u; float f; } x;
  x.u = ((unsigned)v) << 16;
  return x.f;
}
__device__ __forceinline__ u16 f2bf(float f) {
  union { float ff; unsigned u; } x;
  x.ff = f;
  unsigned r = x.u + 0x7fffu + ((x.u >> 16) & 1u);
  return (u16)(r >> 16);
}
// LDS elem index; row stride 512 elems (1KB). 16B-granule XOR swizzle.
__device__ __forceinline__ int swz(int row, int col) {
  int g = ((row & 7) ^ (row >> 3)) & 7;
  return row * 512 + (col ^ (g << 3));
}

__global__ void k_cvt(const float* __restrict__ src, u16* __restrict__ dst, int n) {
  int i = blockIdx.x * 256 + threadIdx.x;
  if (i < n) dst[i] = f2bf(src[i]);
}

__global__ void k_zero(float* __restrict__ pooled) {
  int i = blockIdx.x * 256 + threadIdx.x;
  if (i < B * C) pooled[i] = 0.f;
}

// decoder weights -> bf16, original [layer][co][ci] orientation; f/g keep tap-1 only.
__global__ void k_tdec(const float* __restrict__ dWf, const float* __restrict__ dWg,
                       const float* __restrict__ dWr, const float* __restrict__ dinW,
                       u16* __restrict__ tWf, u16* __restrict__ tWg,
                       u16* __restrict__ tWr, u16* __restrict__ tdin) {
  int i = blockIdx.x * 256 + threadIdx.x;
  if (i < NDEC * C * C) {
    tWf[i] = f2bf(dWf[(size_t)i * 2 + 1]);
    tWg[i] = f2bf(dWg[(size_t)i * 2 + 1]);
    tWr[i] = f2bf(dWr[i]);
  }
  if (i < C * 128) tdin[i] = f2bf(dinW[i]);   // [co][l]
}

__global__ void k_input(const float* __restrict__ x, const float* __restrict__ W,
                        const float* __restrict__ bin, float* __restrict__ h) {
  int idx = blockIdx.x * 256 + threadIdx.x;
  int t = idx & (T - 1);
  int c = (idx >> 12) & (C - 1);
  int b = idx >> 20;
  float xv = x[b * T + t];
  float xp = (t > 0) ? x[b * T + t - 1] : 0.f;
  h[idx] = W[2 * c] * xp + W[2 * c + 1] * xv + bin[c];
}

// One fused gated residual block. grid=256 (b x 64 t-tiles), block=512 (8 waves x 32 co)
__global__ __launch_bounds__(512, 2) void k_enc(
    const float* __restrict__ hin, float* __restrict__ hout, float* __restrict__ pooled,
    const u16* __restrict__ Wf, const float* __restrict__ bfb,
    const u16* __restrict__ Wg, const float* __restrict__ bgb,
    const u16* __restrict__ Wr, const float* __restrict__ brb,
    const u16* __restrict__ Ws, const float* __restrict__ bsb,
    int dil) {
  __shared__ __align__(16) u16 lds[64 * 512];
  const int tid = threadIdx.x;
  const int wave = tid >> 6;
  const int lane = tid & 63;
  const int ncol = lane & 15;
  const int quad = lane >> 4;
  const int wg = blockIdx.x;
  const int b = wg >> 6;
  const int t0 = (wg & 63) * TILE;
  const float* hb = hin + b * C * T;

  const int co0 = wave * 32;
  const int mrow = lane & 15;
  const int kq = quad * 8;
  const u16* ar0 = Wf + (co0 + mrow) * 512;
  const u16* ar1 = Wf + (co0 + 16 + mrow) * 512;
  const u16* ar2 = Wg + (co0 + mrow) * 512;
  const u16* ar3 = Wg + (co0 + 16 + mrow) * 512;

  // ---- preload phase-1 A-weight queue (independent of LDS staging) ----
  bf16x8 aq0[4], aq1[4], aq2[4], aq3[4];
#pragma unroll
  for (int p = 0; p < 4; ++p) {
    const int kk = p * 32 + kq;
    aq0[p] = *(const bf16x8*)(ar0 + kk);
    aq1[p] = *(const bf16x8*)(ar1 + kk);
    aq2[p] = *(const bf16x8*)(ar2 + kk);
    aq3[p] = *(const bf16x8*)(ar3 + kk);
  }

  // ---- stage B1: lds[n][2ci+tap] = bf16(h[ci][t0+n-(tap?0:dil)]) ----
  const int n4 = tid & 15;
  const int cib = tid >> 4;
  float4 v[16];
  const bool fast0 = ((dil & 3) == 0) && (t0 >= dil);
  if (fast0) {
#pragma unroll
    for (int it2 = 0; it2 < 16; ++it2) {
      int ci = (cib + it2 * 32) & 255;
      int tap = it2 >> 3;
      int tb = t0 + n4 * 4 - (tap ? 0 : dil);
      v[it2] = *(const float4*)(hb + ci * T + tb);
    }
  } else {
#pragma unroll
    for (int it2 = 0; it2 < 16; ++it2) {
      int ci = (cib + it2 * 32) & 255;
      int tap = it2 >> 3;
      int tb = t0 + n4 * 4 - (tap ? 0 : dil);
      const float* p = hb + ci * T + tb;
      if (tap) {
        v[it2] = *(const float4*)p;
      } else {
        v[it2].x = (tb + 0 >= 0) ? p[0] : 0.f;
        v[it2].y = (tb + 1 >= 0) ? p[1] : 0.f;
        v[it2].z = (tb + 2 >= 0) ? p[2] : 0.f;
        v[it2].w = (tb + 3 >= 0) ? p[3] : 0.f;
      }
    }
  }
  // pack tap0/tap1 pairs -> u32 LDS writes (same ci: it2 and it2+8)
#pragma unroll
  for (int it2 = 0; it2 < 8; ++it2) {
    int ci = (cib + it2 * 32) & 255;
    const float* p0 = (const float*)&v[it2];
    const float* p1 = (const float*)&v[it2 + 8];
#pragma unroll
    for (int r = 0; r < 4; ++r) {
      unsigned w32 = (unsigned)f2bf(p0[r]) | ((unsigned)f2bf(p1[r]) << 16);
      *(unsigned*)(&lds[swz(n4 * 4 + r, 2 * ci)]) = w32;
    }
  }
  __syncthreads();

  // ---- phase 1: [f;g] = W_fg @ B1,  M=512 K=512 N=64, 4-deep prefetch ----
  f32x4 acc[4][4];
#pragma unroll
  for (int m = 0; m < 4; ++m)
#pragma unroll
    for (int nt = 0; nt < 4; ++nt)
      acc[m][nt] = (f32x4){0.f, 0.f, 0.f, 0.f};

#pragma unroll
  for (int it = 0; it < 16; ++it) {
    const int slot = it & 3;
    const int kk = it * 32 + kq;
    bf16x8 bfr[4];
#pragma unroll
    for (int nt = 0; nt < 4; ++nt)
      bfr[nt] = *(const bf16x8*)(&lds[swz(nt * 16 + ncol, kk)]);
#pragma unroll
    for (int nt = 0; nt < 4; ++nt) {
      acc[0][nt] = __builtin_amdgcn_mfma_f32_16x16x32_bf16(aq0[slot], bfr[nt], acc[0][nt], 0, 0, 0);
      acc[1][nt] = __builtin_amdgcn_mfma_f32_16x16x32_bf16(aq1[slot], bfr[nt], acc[1][nt], 0, 0, 0);
      acc[2][nt] = __builtin_amdgcn_mfma_f32_16x16x32_bf16(aq2[slot], bfr[nt], acc[2][nt], 0, 0, 0);
      acc[3][nt] = __builtin_amdgcn_mfma_f32_16x16x32_bf16(aq3[slot], bfr[nt], acc[3][nt], 0, 0, 0);
    }
    if (it < 12) {
      const int kn = (it + 4) * 32 + kq;
      aq0[slot] = *(const bf16x8*)(ar0 + kn);
      aq1[slot] = *(const bf16x8*)(ar1 + kn);
      aq2[slot] = *(const bf16x8*)(ar2 + kn);
      aq3[slot] = *(const bf16x8*)(ar3 + kn);
    }
  }

  // ---- preload phase-2 weight queue (independent of B2 LDS) ----
  const u16* rr0 = Wr + (co0 + mrow) * 256;
  const u16* rr1 = Wr + (co0 + 16 + mrow) * 256;
  const u16* rr2 = Ws + (co0 + mrow) * 256;
  const u16* rr3 = Ws + (co0 + 16 + mrow) * 256;
  bf16x8 rq0[4], rq1[4], rq2[4], rq3[4];
#pragma unroll
  for (int p = 0; p < 4; ++p) {
    const int kk = p * 32 + kq;
    rq0[p] = *(const bf16x8*)(rr0 + kk);
    rq1[p] = *(const bf16x8*)(rr1 + kk);
    rq2[p] = *(const bf16x8*)(rr2 + kk);
    rq3[p] = *(const bf16x8*)(rr3 + kk);
  }
  __syncthreads();   // all waves done reading B1

  // ---- gating -> LDS as B2[k=co][n] ----
#pragma unroll
  for (int j = 0; j < 2; ++j) {
    const int cob = co0 + j * 16 + quad * 4;
    float bfv[4], bgv[4];
#pragma unroll
    for (int r = 0; r < 4; ++r) {
      bfv[r] = bfb[cob + r];
      bgv[r] = bgb[cob + r];
    }
#pragma unroll
    for (int nt = 0; nt < 4; ++nt) {
      const int n = nt * 16 + ncol;
      u16 pk[4];
#pragma unroll
      for (int r = 0; r < 4; ++r) {
        float fv = acc[j][nt][r] + bfv[r];
        float gv = acc[2 + j][nt][r] + bgv[r];
        float th = 1.f - 2.f / (__expf(2.f * fv) + 1.f);
        float sg = 1.f / (1.f + __expf(-gv));
        pk[r] = f2bf(th * sg);
      }
      uint2 w;
      w.x = (unsigned)pk[0] | ((unsigned)pk[1] << 16);
      w.y = (unsigned)pk[2] | ((unsigned)pk[3] << 16);
      *(uint2*)(&lds[swz(n, cob)]) = w;
    }
  }
  __syncthreads();

  // ---- phase 2: [res;skip] = W_rs @ out,  M=512 K=256 N=64, 4-deep prefetch ----
  f32x4 acc2[4][4];
#pragma unroll
  for (int m = 0; m < 4; ++m)
#pragma unroll
    for (int nt = 0; nt < 4; ++nt)
      acc2[m][nt] = (f32x4){0.f, 0.f, 0.f, 0.f};

#pragma unroll
  for (int it = 0; it < 8; ++it) {
    const int slot = it & 3;
    const int kk = it * 32 + kq;
    bf16x8 bfr[4];
#pragma unroll
    for (int nt = 0; nt < 4; ++nt)
      bfr[nt] = *(const bf16x8*)(&lds[swz(nt * 16 + ncol, kk)]);
#pragma unroll
    for (int nt = 0; nt < 4; ++nt) {
      acc2[0][nt] = __builtin_amdgcn_mfma_f32_16x16x32_bf16(rq0[slot], bfr[nt], acc2[0][nt], 0, 0, 0);
      acc2[1][nt] = __builtin_amdgcn_mfma_f32_16x16x32_bf16(rq1[slot], bfr[nt], acc2[1][nt], 0, 0, 0);
      acc2[2][nt] = __builtin_amdgcn_mfma_f32_16x16x32_bf16(rq2[slot], bfr[nt], acc2[2][nt], 0, 0, 0);
      acc2[3][nt] = __builtin_amdgcn_mfma_f32_16x16x32_bf16(rq3[slot], bfr[nt], acc2[3][nt], 0, 0, 0);
    }
    if (it < 4) {
      const int kn = (it + 4) * 32 + kq;
      rq0[slot] = *(const bf16x8*)(rr0 + kn);
      rq1[slot] = *(const bf16x8*)(rr1 + kn);
      rq2[slot] = *(const bf16x8*)(rr2 + kn);
      rq3[slot] = *(const bf16x8*)(rr3 + kn);
    }
  }

  // ---- epilogue: residual write (f32) + skip reduce into pooled ----
  float hold[32];
  float brv[2][4];
#pragma unroll
  for (int m = 0; m < 2; ++m)
#pragma unroll
    for (int r = 0; r < 4; ++r)
      brv[m][r] = brb[co0 + m * 16 + quad * 4 + r];
#pragma unroll
  for (int m = 0; m < 2; ++m)
#pragma unroll
    for (int nt = 0; nt < 4; ++nt)
#pragma unroll
      for (int r = 0; r < 4; ++r)
        hold[(m * 4 + nt) * 4 + r] =
            hb[(co0 + m * 16 + quad * 4 + r) * T + (t0 + nt * 16 + ncol)];

  float* ho = hout + b * C * T;
#pragma unroll
  for (int m = 0; m < 2; ++m)
#pragma unroll
    for (int nt = 0; nt < 4; ++nt)
#pragma unroll
      for (int r = 0; r < 4; ++r)
        ho[(co0 + m * 16 + quad * 4 + r) * T + (t0 + nt * 16 + ncol)] =
            acc2[m][nt][r] + brv[m][r] + hold[(m * 4 + nt) * 4 + r];

  float* pb = pooled + b * C;
#pragma unroll
  for (int m = 0; m < 2; ++m) {
    const int cob = co0 + m * 16 + quad * 4;
#pragma unroll
    for (int r = 0; r < 4; ++r) {
      float s = acc2[2 + m][0][r] + acc2[2 + m][1][r] + acc2[2 + m][2][r] + acc2[2 + m][3][r];
      s += __shfl_xor(s, 1);
      s += __shfl_xor(s, 2);
      s += __shfl_xor(s, 4);
      s += __shfl_xor(s, 8);
      if (ncol == 0) atomicAdd(&pb[cob + r], s + 64.f * bsb[cob + r]);
    }
  }
}

// wave-per-dot FC: 1024 dots (b x {mu,lv} x 128), K=256. grid=16 x 256.
__global__ __launch_bounds__(256) void k_fc(
    const float* __restrict__ pooled,
    const float* __restrict__ muW, const float* __restrict__ mub,
    const float* __restrict__ lvW, const float* __restrict__ lvb,
    float* __restrict__ mlbuf, float* __restrict__ dout) {
  __shared__ float pm[B * C];
  const int tid = threadIdx.x;
  for (int i = tid; i < B * C; i += 256) pm[i] = pooled[i] * (1.f / (float)T);
  __syncthreads();
  const int waveG = blockIdx.x * 4 + (tid >> 6);
  const int lane = tid & 63;
  for (int j = 0; j < 16; ++j) {
    int d = waveG * 16 + j;
    int b = d >> 8, r = d & 255, which = r >> 7, l = r & 127;
    const float* Wrow = (which ? lvW : muW) + l * C;
    const float* p = pm + b * C;
    float s = Wrow[lane] * p[lane] + Wrow[lane + 64] * p[lane + 64] +
              Wrow[lane + 128] * p[lane + 128] + Wrow[lane + 192] * p[lane + 192];
#pragma unroll
    for (int off = 32; off; off >>= 1) s += __shfl_xor(s, off);
    if (lane == 0) {
      float val = s + (which ? lvb[l] : mub[l]);
      mlbuf[which * 512 + b * 128 + l] = val;
      dout[4 + which * 512 + b * 128 + l] = val;
    }
  }
}

// Decoder (T=1) as MFMA: one block, 1024 threads = 16 waves, wave w owns co-tile [16w,16w+16).
// A = activations in LDS (bf16, row pad 8), B = bf16 weights [co][ci] via b128 loads.
__global__ __launch_bounds__(1024) void k_dec(
    const float* __restrict__ mlbuf, const float* __restrict__ eps,
    const u16* __restrict__ tdin, const float* __restrict__ dinb,
    const u16* __restrict__ tWf, const float* __restrict__ dbf,
    const u16* __restrict__ tWg, const float* __restrict__ dbg,
    const u16* __restrict__ tWr, const float* __restrict__ dbr,
    const float* __restrict__ outW, const float* __restrict__ outb,
    float* __restrict__ dout) {
  __shared__ __align__(16) u16 Ah[16][264];   // h2 (bf16): rows=batch(0..3 valid), cols=ci
  __shared__ __align__(16) u16 Ao[16][264];   // gated activations o (bf16)
  __shared__ float h2f[4][256];
  __shared__ float outred[4];
  const int tid = threadIdx.x;
  const int wave = tid >> 6;
  const int lane = tid & 63;
  const int ncol = lane & 15;
  const int quad = lane >> 4;
  const int kq = quad * 8;
  const int co = wave * 16 + ncol;   // B-operand column this lane produces

  // z into Ah rows 0..3, cols 0..127
  if (tid < 512) {
    int b = tid >> 7, l = tid & 127;
    float mu = mlbuf[b * 128 + l];
    float lv = mlbuf[512 + b * 128 + l];
    Ah[b][l] = f2bf(mu + eps[b * 128 + l] * expf(0.5f * lv));
  }
  if (tid < 4) outred[tid] = 0.f;
  __syncthreads();

  // dec_in: h2 = dinW @ z  (M=16 pad, K=128, N=256)
  {
    f32x4 acch = (f32x4){0.f, 0.f, 0.f, 0.f};
    const u16* wp = tdin + co * 128;
#pragma unroll
    for (int it = 0; it < 4; ++it) {
      const int kk = it * 32 + kq;
      bf16x8 af = *(const bf16x8*)(&Ah[ncol][kk]);
      bf16x8 bfrag = *(const bf16x8*)(wp + kk);
      acch = __builtin_amdgcn_mfma_f32_16x16x32_bf16(af, bfrag, acch, 0, 0, 0);
    }
    __syncthreads();   // everyone done reading z from Ah
    if (quad == 0) {
      float bias = dinb[co];
#pragma unroll
      for (int r = 0; r < 4; ++r) {
        float hv = acch[r] + bias;
        h2f[r][co] = hv;
        Ah[r][co] = f2bf(hv);
      }
    }
  }
  __syncthreads();

  for (int i = 0; i < NDEC; ++i) {
    // f/g GEMM: K=256
    f32x4 accf = (f32x4){0.f, 0.f, 0.f, 0.f};
    f32x4 accg = (f32x4){0.f, 0.f, 0.f, 0.f};
    const u16* wf = tWf + (size_t)(i * C + co) * C;
    const u16* wg = tWg + (size_t)(i * C + co) * C;
#pragma unroll
    for (int it = 0; it < 8; ++it) {
      const int kk = it * 32 + kq;
      bf16x8 af = *(const bf16x8*)(&Ah[ncol][kk]);
      bf16x8 bf_ = *(const bf16x8*)(wf + kk);
      bf16x8 bg_ = *(const bf16x8*)(wg + kk);
      accf = __builtin_amdgcn_mfma_f32_16x16x32_bf16(af, bf_, accf, 0, 0, 0);
      accg = __builtin_amdgcn_mfma_f32_16x16x32_bf16(af, bg_, accg, 0, 0, 0);
    }
    if (quad == 0) {
      float bfv = dbf[i * C + co];
      float bgv = dbg[i * C + co];
#pragma unroll
      for (int r = 0; r < 4; ++r) {
        float fv = accf[r] + bfv;
        float gv = accg[r] + bgv;
        float th = 1.f - 2.f / (__expf(2.f * fv) + 1.f);
        float sg = 1.f / (1.f + __expf(-gv));
        Ao[r][co] = f2bf(th * sg);
      }
    }
    __syncthreads();   // o complete

    // res GEMM: K=256 on Ao
    f32x4 accr = (f32x4){0.f, 0.f, 0.f, 0.f};
    const u16* wr = tWr + (size_t)(i * C + co) * C;
#pragma unroll
    for (int it = 0; it < 8; ++it) {
      const int kk = it * 32 + kq;
      bf16x8 af = *(const bf16x8*)(&Ao[ncol][kk]);
      bf16x8 br_ = *(const bf16x8*)(wr + kk);
      accr = __builtin_amdgcn_mfma_f32_16x16x32_bf16(af, br_, accr, 0, 0, 0);
    }
    if (quad == 0) {
      float brv = dbr[i * C + co];
#pragma unroll
      for (int r = 0; r < 4; ++r) {
        float hv = h2f[r][co] + accr[r] + brv;
        h2f[r][co] = hv;
        Ah[r][co] = f2bf(hv);
      }
    }
    __syncthreads();   // h2 update visible
  }

  // y[b] = outW . h2[b] + outb
  {
    int b = tid >> 8, c = tid & 255;
    float val = outW[c] * h2f[b][c];
#pragma unroll
    for (int off = 32; off; off >>= 1) val += __shfl_xor(val, off);
    if (lane == 0) atomicAdd(&outred[b], val);
  }
  __syncthreads();
  if (tid < 4) dout[tid] = outred[tid] + outb[0];
}

extern "C" void kernel_launch(void* const* d_in, const int* in_sizes, int n_in,
                              void* d_out, int out_size, void* d_ws, size_t ws_size,
                              hipStream_t stream) {
  const float* x      = (const float*)d_in[0];
  const float* eps    = (const float*)d_in[1];
  const float* encinW = (const float*)d_in[2];
  const float* encinb = (const float*)d_in[3];
  const float* encWf  = (const float*)d_in[4];
  const float* encbf  = (const float*)d_in[5];
  const float* encWg  = (const float*)d_in[6];
  const float* encbg  = (const float*)d_in[7];
  const float* encWr  = (const float*)d_in[8];
  const float* encbr  = (const float*)d_in[9];
  const float* encWs  = (const float*)d_in[10];
  const float* encbs  = (const float*)d_in[11];
  const float* muW    = (const float*)d_in[12];
  const float* mub    = (const float*)d_in[13];
  const float* lvW    = (const float*)d_in[14];
  const float* lvb    = (const float*)d_in[15];
  const float* dinW   = (const float*)d_in[16];
  const float* dinb   = (const float*)d_in[17];
  const float* dWf    = (const float*)d_in[18];
  const float* dbf    = (const float*)d_in[19];
  const float* dWg    = (const float*)d_in[20];
  const float* dbg    = (const float*)d_in[21];
  const float* dWr    = (const float*)d_in[22];
  const float* dbr    = (const float*)d_in[23];
  const float* outW   = (const float*)d_in[24];
  const float* outb   = (const float*)d_in[25];
  float* dout = (float*)d_out;

  const int nFG = NENC * C * C * 2;
  const int nRS = NENC * C * C;
  const int nTD = NDEC * C * C;

  char* ws = (char*)d_ws;
  float* hA = (float*)ws;
  float* hB = hA + (size_t)B * C * T;
  float* pooled = hB + (size_t)B * C * T;
  float* mlbuf = pooled + B * C;
  u16* wWf = (u16*)(mlbuf + 1024);
  u16* wWg = wWf + (size_t)nFG;
  u16* wWr = wWg + (size_t)nFG;
  u16* wWs = wWr + (size_t)nRS;
  u16* tWf = wWs + (size_t)nRS;
  u16* tWg = tWf + (size_t)nTD;
  u16* tWr = tWg + (size_t)nTD;
  u16* tdin = tWr + (size_t)nTD;   // [256][128] bf16

  k_cvt<<<(nFG + 255) / 256, 256, 0, stream>>>(encWf, wWf, nFG);
  k_cvt<<<(nFG + 255) / 256, 256, 0, stream>>>(encWg, wWg, nFG);
  k_cvt<<<(nRS + 255) / 256, 256, 0, stream>>>(encWr, wWr, nRS);
  k_cvt<<<(nRS + 255) / 256, 256, 0, stream>>>(encWs, wWs, nRS);
  k_tdec<<<(nTD + 255) / 256, 256, 0, stream>>>(dWf, dWg, dWr, dinW, tWf, tWg, tWr, tdin);

  k_zero<<<4, 256, 0, stream>>>(pooled);
  k_input<<<(B * C * T) / 256, 256, 0, stream>>>(x, encinW, encinb, hA);

  for (int i = 0; i < NENC; ++i) {
    const int dil = 1 << (i % 10);
    const float* hi = (i & 1) ? hB : hA;
    float* ho = (i & 1) ? hA : hB;
    k_enc<<<256, 512, 0, stream>>>(
        hi, ho, pooled,
        wWf + (size_t)i * C * C * 2, encbf + (size_t)i * C,
        wWg + (size_t)i * C * C * 2, encbg + (size_t)i * C,
        wWr + (size_t)i * C * C,     encbr + (size_t)i * C,
        wWs + (size_t)i * C * C,     encbs + (size_t)i * C,
        dil);
  }

  k_fc<<<16, 256, 0, stream>>>(pooled, muW, mub, lvW, lvb, mlbuf, dout);
  k_dec<<<1, 1024, 0, stream>>>(mlbuf, eps, tdin, dinb, tWf, dbf, tWg, dbg,
                                tWr, dbr, outW, outb, dout);
}

// Round 5
// 1634.959 us; speedup vs baseline: 1.9439x; 1.2254x over previous
//
#include <hip/hip_runtime.h>

typedef unsigned short u16;
typedef __attribute__((ext_vector_type(8))) __bf16 bf16x8;
typedef __attribute__((ext_vector_type(4))) float f32x4;

constexpr int C = 256;
constexpr int T = 4096;
constexpr int B = 4;
constexpr int NENC = 40;
constexpr int NDEC = 10;
constexpr int TILE = 64;

__device__ __forceinline__ float bf2f(u16 v) {
  union { unsigned u; float f; } x;
  x.u = ((unsigned)v) << 16;
  return x.f;
}
__device__ __forceinline__ u16 f2bf(float f) {
  union { float ff; unsigned u; } x;
  x.ff = f;
  unsigned r = x.u + 0x7fffu + ((x.u >> 16) & 1u);
  return (u16)(r >> 16);
}
// B1 LDS elem index; row stride 512 elems (1KB), 16B-granule XOR swizzle.
__device__ __forceinline__ int swz(int row, int col) {
  int g = ((row & 7) ^ (row >> 3)) & 7;
  return row * 512 + (col ^ (g << 3));
}

typedef __attribute__((address_space(1))) const unsigned int* gp1_t;
typedef __attribute__((address_space(3))) unsigned int* lp3_t;
__device__ __forceinline__ void gl_lds16(const u16* g, u16* l) {
  // async DMA: 64 lanes x 16B; global addr per-lane, LDS dest = uniform + lane*16
  __builtin_amdgcn_global_load_lds((gp1_t)(const void*)g, (lp3_t)(void*)l, 16, 0, 0);
}

__global__ void k_cvt(const float* __restrict__ src, u16* __restrict__ dst, int n) {
  int i = blockIdx.x * 256 + threadIdx.x;
  if (i < n) dst[i] = f2bf(src[i]);
}

__global__ void k_zero(float* __restrict__ pooled) {
  int i = blockIdx.x * 256 + threadIdx.x;
  if (i < B * C) pooled[i] = 0.f;
}

// decoder weights -> bf16, [layer][co][ci]; f/g keep tap-1 only.
__global__ void k_tdec(const float* __restrict__ dWf, const float* __restrict__ dWg,
                       const float* __restrict__ dWr, const float* __restrict__ dinW,
                       u16* __restrict__ tWf, u16* __restrict__ tWg,
                       u16* __restrict__ tWr, u16* __restrict__ tdin) {
  int i = blockIdx.x * 256 + threadIdx.x;
  if (i < NDEC * C * C) {
    tWf[i] = f2bf(dWf[(size_t)i * 2 + 1]);
    tWg[i] = f2bf(dWg[(size_t)i * 2 + 1]);
    tWr[i] = f2bf(dWr[i]);
  }
  if (i < C * 128) tdin[i] = f2bf(dinW[i]);
}

__global__ void k_input(const float* __restrict__ x, const float* __restrict__ W,
                        const float* __restrict__ bin, float* __restrict__ h) {
  int idx = blockIdx.x * 256 + threadIdx.x;
  int t = idx & (T - 1);
  int c = (idx >> 12) & (C - 1);
  int b = idx >> 20;
  float xv = x[b * T + t];
  float xp = (t > 0) ? x[b * T + t - 1] : 0.f;
  h[idx] = W[2 * c] * xp + W[2 * c + 1] * xv + bin[c];
}

// Fused gated residual block. grid=256 (b x 64 t-tiles), block=512 (8 waves x 32 co).
// Dynamic LDS 128KB: B1 [64n][512k] (64KB) + wave-private weight double-buffer (64KB).
__global__ __launch_bounds__(512, 2) void k_enc(
    const float* __restrict__ hin, float* __restrict__ hout, float* __restrict__ pooled,
    const u16* __restrict__ Wf, const float* __restrict__ bfb,
    const u16* __restrict__ Wg, const float* __restrict__ bgb,
    const u16* __restrict__ Wr, const float* __restrict__ brb,
    const u16* __restrict__ Ws, const float* __restrict__ bsb,
    int dil) {
  extern __shared__ __align__(16) u16 smem[];
  u16* wb = smem + 64 * 512;               // weight stream buffers: 2 x 16384 elems
  const int tid = threadIdx.x;
  const int wave = tid >> 6;
  const int lane = tid & 63;
  const int ncol = lane & 15;
  const int quad = lane >> 4;
  const int wg = blockIdx.x;
  const int b = wg >> 6;
  const int t0 = (wg & 63) * TILE;
  const float* hb = hin + b * C * T;

  const int co0 = wave * 32;
  const int mrow = lane & 15;
  const int kq = quad * 8;
  // DMA source lane mapping: row16 = lane>>2, granule p' = (lane&3) ^ (row16&3)
  const int r16 = lane >> 2;
  const int psw8 = (((lane & 3) ^ (r16 & 3)) << 3);
  // per-lane row base pointers, phase 1 (K=512)
  const u16* pa0 = Wf + (co0 + r16) * 512 + psw8;
  const u16* pa1 = Wf + (co0 + 16 + r16) * 512 + psw8;
  const u16* pa2 = Wg + (co0 + r16) * 512 + psw8;
  const u16* pa3 = Wg + (co0 + 16 + r16) * 512 + psw8;
  u16* wreg0 = wb + wave * 2048;           // buffer 0, this wave's region
  u16* wreg1 = wb + 16384 + wave * 2048;   // buffer 1
  // A-frag read offset within a stream region
  const int aoff = mrow * 32 + ((quad ^ (mrow & 3)) << 3);

  // ---- issue phase-1 chunks 0,1 (land by the staging barrier) ----
#pragma unroll
  for (int cc = 0; cc < 2; ++cc) {
    u16* ld = cc ? wreg1 : wreg0;
    gl_lds16(pa0 + cc * 32, ld);
    gl_lds16(pa1 + cc * 32, ld + 512);
    gl_lds16(pa2 + cc * 32, ld + 1024);
    gl_lds16(pa3 + cc * 32, ld + 1536);
  }

  // ---- stage B1: smem[n][2ci+tap] = bf16(h[ci][t0+n-(tap?0:dil)]) ----
  const int n4 = tid & 15;
  const int cib = tid >> 4;
  float4 v[16];
  const bool fast0 = ((dil & 3) == 0) && (t0 >= dil);
  if (fast0) {
#pragma unroll
    for (int it2 = 0; it2 < 16; ++it2) {
      int ci = (cib + it2 * 32) & 255;
      int tap = it2 >> 3;
      int tb = t0 + n4 * 4 - (tap ? 0 : dil);
      v[it2] = *(const float4*)(hb + ci * T + tb);
    }
  } else {
#pragma unroll
    for (int it2 = 0; it2 < 16; ++it2) {
      int ci = (cib + it2 * 32) & 255;
      int tap = it2 >> 3;
      int tb = t0 + n4 * 4 - (tap ? 0 : dil);
      const float* p = hb + ci * T + tb;
      if (tap) {
        v[it2] = *(const float4*)p;
      } else {
        v[it2].x = (tb + 0 >= 0) ? p[0] : 0.f;
        v[it2].y = (tb + 1 >= 0) ? p[1] : 0.f;
        v[it2].z = (tb + 2 >= 0) ? p[2] : 0.f;
        v[it2].w = (tb + 3 >= 0) ? p[3] : 0.f;
      }
    }
  }
#pragma unroll
  for (int it2 = 0; it2 < 8; ++it2) {
    int ci = (cib + it2 * 32) & 255;
    const float* p0 = (const float*)&v[it2];
    const float* p1 = (const float*)&v[it2 + 8];
#pragma unroll
    for (int r = 0; r < 4; ++r) {
      unsigned w32 = (unsigned)f2bf(p0[r]) | ((unsigned)f2bf(p1[r]) << 16);
      *(unsigned*)(&smem[swz(n4 * 4 + r, 2 * ci)]) = w32;
    }
  }
  __syncthreads();   // drains vmcnt(0): chunks 0,1 landed

  // ---- phase 1: [f;g] = W_fg @ B1, M=512 K=512 N=64, LDS-streamed weights ----
  f32x4 acc[4][4];
#pragma unroll
  for (int m = 0; m < 4; ++m)
#pragma unroll
    for (int nt = 0; nt < 4; ++nt)
      acc[m][nt] = (f32x4){0.f, 0.f, 0.f, 0.f};

#pragma unroll
  for (int c = 0; c < 16; ++c) {
    if (c < 15) asm volatile("s_waitcnt vmcnt(4)" ::: "memory");
    else        asm volatile("s_waitcnt vmcnt(0)" ::: "memory");
    const u16* wr_ = (c & 1) ? wreg1 : wreg0;
    bf16x8 af0 = *(const bf16x8*)(wr_ + aoff);
    bf16x8 af1 = *(const bf16x8*)(wr_ + 512 + aoff);
    bf16x8 af2 = *(const bf16x8*)(wr_ + 1024 + aoff);
    bf16x8 af3 = *(const bf16x8*)(wr_ + 1536 + aoff);
    const int kk = c * 32 + kq;
    bf16x8 bfr[4];
#pragma unroll
    for (int nt = 0; nt < 4; ++nt)
      bfr[nt] = *(const bf16x8*)(&smem[swz(nt * 16 + ncol, kk)]);
#pragma unroll
    for (int nt = 0; nt < 4; ++nt) {
      acc[0][nt] = __builtin_amdgcn_mfma_f32_16x16x32_bf16(af0, bfr[nt], acc[0][nt], 0, 0, 0);
      acc[1][nt] = __builtin_amdgcn_mfma_f32_16x16x32_bf16(af1, bfr[nt], acc[1][nt], 0, 0, 0);
      acc[2][nt] = __builtin_amdgcn_mfma_f32_16x16x32_bf16(af2, bfr[nt], acc[2][nt], 0, 0, 0);
      acc[3][nt] = __builtin_amdgcn_mfma_f32_16x16x32_bf16(af3, bfr[nt], acc[3][nt], 0, 0, 0);
    }
    if (c + 2 < 16) {
      // ds_reads of this chunk retired before we overwrite its buffer
      asm volatile("s_waitcnt lgkmcnt(0)" ::: "memory");
      u16* ld = (c & 1) ? wreg1 : wreg0;
      const int go = (c + 2) * 32;
      gl_lds16(pa0 + go, ld);
      gl_lds16(pa1 + go, ld + 512);
      gl_lds16(pa2 + go, ld + 1024);
      gl_lds16(pa3 + go, ld + 1536);
    }
  }

  // ---- issue phase-2 chunks 0,1 (land by next barrier) ----
  const u16* pr0 = Wr + (co0 + r16) * 256 + psw8;
  const u16* pr1 = Wr + (co0 + 16 + r16) * 256 + psw8;
  const u16* pr2 = Ws + (co0 + r16) * 256 + psw8;
  const u16* pr3 = Ws + (co0 + 16 + r16) * 256 + psw8;
#pragma unroll
  for (int cc = 0; cc < 2; ++cc) {
    u16* ld = cc ? wreg1 : wreg0;
    gl_lds16(pr0 + cc * 32, ld);
    gl_lds16(pr1 + cc * 32, ld + 512);
    gl_lds16(pr2 + cc * 32, ld + 1024);
    gl_lds16(pr3 + cc * 32, ld + 1536);
  }
  __syncthreads();   // B1 reads done + p2 chunks 0,1 landed

  // ---- gating -> LDS as B2[k=co][n] (overwrites B1 area) ----
#pragma unroll
  for (int j = 0; j < 2; ++j) {
    const int cob = co0 + j * 16 + quad * 4;
    float bfv[4], bgv[4];
#pragma unroll
    for (int r = 0; r < 4; ++r) {
      bfv[r] = bfb[cob + r];
      bgv[r] = bgb[cob + r];
    }
#pragma unroll
    for (int nt = 0; nt < 4; ++nt) {
      const int n = nt * 16 + ncol;
      u16 pk[4];
#pragma unroll
      for (int r = 0; r < 4; ++r) {
        float fv = acc[j][nt][r] + bfv[r];
        float gv = acc[2 + j][nt][r] + bgv[r];
        float th = 1.f - 2.f / (__expf(2.f * fv) + 1.f);
        float sg = 1.f / (1.f + __expf(-gv));
        pk[r] = f2bf(th * sg);
      }
      uint2 w;
      w.x = (unsigned)pk[0] | ((unsigned)pk[1] << 16);
      w.y = (unsigned)pk[2] | ((unsigned)pk[3] << 16);
      *(uint2*)(&smem[swz(n, cob)]) = w;
    }
  }
  __syncthreads();

  // ---- phase 2: [res;skip] = W_rs @ out, M=512 K=256 N=64 ----
  f32x4 acc2[4][4];
#pragma unroll
  for (int m = 0; m < 4; ++m)
#pragma unroll
    for (int nt = 0; nt < 4; ++nt)
      acc2[m][nt] = (f32x4){0.f, 0.f, 0.f, 0.f};

#pragma unroll
  for (int c = 0; c < 8; ++c) {
    if (c < 7) asm volatile("s_waitcnt vmcnt(4)" ::: "memory");
    else       asm volatile("s_waitcnt vmcnt(0)" ::: "memory");
    const u16* wr_ = (c & 1) ? wreg1 : wreg0;
    bf16x8 af0 = *(const bf16x8*)(wr_ + aoff);
    bf16x8 af1 = *(const bf16x8*)(wr_ + 512 + aoff);
    bf16x8 af2 = *(const bf16x8*)(wr_ + 1024 + aoff);
    bf16x8 af3 = *(const bf16x8*)(wr_ + 1536 + aoff);
    const int kk = c * 32 + kq;
    bf16x8 bfr[4];
#pragma unroll
    for (int nt = 0; nt < 4; ++nt)
      bfr[nt] = *(const bf16x8*)(&smem[swz(nt * 16 + ncol, kk)]);
#pragma unroll
    for (int nt = 0; nt < 4; ++nt) {
      acc2[0][nt] = __builtin_amdgcn_mfma_f32_16x16x32_bf16(af0, bfr[nt], acc2[0][nt], 0, 0, 0);
      acc2[1][nt] = __builtin_amdgcn_mfma_f32_16x16x32_bf16(af1, bfr[nt], acc2[1][nt], 0, 0, 0);
      acc2[2][nt] = __builtin_amdgcn_mfma_f32_16x16x32_bf16(af2, bfr[nt], acc2[2][nt], 0, 0, 0);
      acc2[3][nt] = __builtin_amdgcn_mfma_f32_16x16x32_bf16(af3, bfr[nt], acc2[3][nt], 0, 0, 0);
    }
    if (c + 2 < 8) {
      asm volatile("s_waitcnt lgkmcnt(0)" ::: "memory");
      u16* ld = (c & 1) ? wreg1 : wreg0;
      const int go = (c + 2) * 32;
      gl_lds16(pr0 + go, ld);
      gl_lds16(pr1 + go, ld + 512);
      gl_lds16(pr2 + go, ld + 1024);
      gl_lds16(pr3 + go, ld + 1536);
    }
  }

  // ---- epilogue: residual write (f32) + skip reduce into pooled ----
  float hold[32];
  float brv[2][4];
#pragma unroll
  for (int m = 0; m < 2; ++m)
#pragma unroll
    for (int r = 0; r < 4; ++r)
      brv[m][r] = brb[co0 + m * 16 + quad * 4 + r];
#pragma unroll
  for (int m = 0; m < 2; ++m)
#pragma unroll
    for (int nt = 0; nt < 4; ++nt)
#pragma unroll
      for (int r = 0; r < 4; ++r)
        hold[(m * 4 + nt) * 4 + r] =
            hb[(co0 + m * 16 + quad * 4 + r) * T + (t0 + nt * 16 + ncol)];

  float* ho = hout + b * C * T;
#pragma unroll
  for (int m = 0; m < 2; ++m)
#pragma unroll
    for (int nt = 0; nt < 4; ++nt)
#pragma unroll
      for (int r = 0; r < 4; ++r)
        ho[(co0 + m * 16 + quad * 4 + r) * T + (t0 + nt * 16 + ncol)] =
            acc2[m][nt][r] + brv[m][r] + hold[(m * 4 + nt) * 4 + r];

  float* pb = pooled + b * C;
#pragma unroll
  for (int m = 0; m < 2; ++m) {
    const int cob = co0 + m * 16 + quad * 4;
#pragma unroll
    for (int r = 0; r < 4; ++r) {
      float s = acc2[2 + m][0][r] + acc2[2 + m][1][r] + acc2[2 + m][2][r] + acc2[2 + m][3][r];
      s += __shfl_xor(s, 1);
      s += __shfl_xor(s, 2);
      s += __shfl_xor(s, 4);
      s += __shfl_xor(s, 8);
      if (ncol == 0) atomicAdd(&pb[cob + r], s + 64.f * bsb[cob + r]);
    }
  }
}

// wave-per-dot FC: 1024 dots (b x {mu,lv} x 128), K=256. grid=16 x 256.
__global__ __launch_bounds__(256) void k_fc(
    const float* __restrict__ pooled,
    const float* __restrict__ muW, const float* __restrict__ mub,
    const float* __restrict__ lvW, const float* __restrict__ lvb,
    float* __restrict__ mlbuf, float* __restrict__ dout) {
  __shared__ float pm[B * C];
  const int tid = threadIdx.x;
  for (int i = tid; i < B * C; i += 256) pm[i] = pooled[i] * (1.f / (float)T);
  __syncthreads();
  const int waveG = blockIdx.x * 4 + (tid >> 6);
  const int lane = tid & 63;
  for (int j = 0; j < 16; ++j) {
    int d = waveG * 16 + j;
    int b = d >> 8, r = d & 255, which = r >> 7, l = r & 127;
    const float* Wrow = (which ? lvW : muW) + l * C;
    const float* p = pm + b * C;
    float s = Wrow[lane] * p[lane] + Wrow[lane + 64] * p[lane + 64] +
              Wrow[lane + 128] * p[lane + 128] + Wrow[lane + 192] * p[lane + 192];
#pragma unroll
    for (int off = 32; off; off >>= 1) s += __shfl_xor(s, off);
    if (lane == 0) {
      float val = s + (which ? lvb[l] : mub[l]);
      mlbuf[which * 512 + b * 128 + l] = val;
      dout[4 + which * 512 + b * 128 + l] = val;
    }
  }
}

// Decoder (T=1) as MFMA: one block, 1024 threads = 16 waves.
__global__ __launch_bounds__(1024) void k_dec(
    const float* __restrict__ mlbuf, const float* __restrict__ eps,
    const u16* __restrict__ tdin, const float* __restrict__ dinb,
    const u16* __restrict__ tWf, const float* __restrict__ dbf,
    const u16* __restrict__ tWg, const float* __restrict__ dbg,
    const u16* __restrict__ tWr, const float* __restrict__ dbr,
    const float* __restrict__ outW, const float* __restrict__ outb,
    float* __restrict__ dout) {
  __shared__ __align__(16) u16 Ah[16][264];
  __shared__ __align__(16) u16 Ao[16][264];
  __shared__ float h2f[4][256];
  __shared__ float outred[4];
  const int tid = threadIdx.x;
  const int wave = tid >> 6;
  const int lane = tid & 63;
  const int ncol = lane & 15;
  const int quad = lane >> 4;
  const int kq = quad * 8;
  const int co = wave * 16 + ncol;

  if (tid < 512) {
    int b = tid >> 7, l = tid & 127;
    float mu = mlbuf[b * 128 + l];
    float lv = mlbuf[512 + b * 128 + l];
    Ah[b][l] = f2bf(mu + eps[b * 128 + l] * expf(0.5f * lv));
  }
  if (tid < 4) outred[tid] = 0.f;
  __syncthreads();

  {
    f32x4 acch = (f32x4){0.f, 0.f, 0.f, 0.f};
    const u16* wp = tdin + co * 128;
#pragma unroll
    for (int it = 0; it < 4; ++it) {
      const int kk = it * 32 + kq;
      bf16x8 af = *(const bf16x8*)(&Ah[ncol][kk]);
      bf16x8 bfrag = *(const bf16x8*)(wp + kk);
      acch = __builtin_amdgcn_mfma_f32_16x16x32_bf16(af, bfrag, acch, 0, 0, 0);
    }
    __syncthreads();
    if (quad == 0) {
      float bias = dinb[co];
#pragma unroll
      for (int r = 0; r < 4; ++r) {
        float hv = acch[r] + bias;
        h2f[r][co] = hv;
        Ah[r][co] = f2bf(hv);
      }
    }
  }
  __syncthreads();

  for (int i = 0; i < NDEC; ++i) {
    f32x4 accf = (f32x4){0.f, 0.f, 0.f, 0.f};
    f32x4 accg = (f32x4){0.f, 0.f, 0.f, 0.f};
    const u16* wf = tWf + (size_t)(i * C + co) * C;
    const u16* wg = tWg + (size_t)(i * C + co) * C;
#pragma unroll
    for (int it = 0; it < 8; ++it) {
      const int kk = it * 32 + kq;
      bf16x8 af = *(const bf16x8*)(&Ah[ncol][kk]);
      bf16x8 bf_ = *(const bf16x8*)(wf + kk);
      bf16x8 bg_ = *(const bf16x8*)(wg + kk);
      accf = __builtin_amdgcn_mfma_f32_16x16x32_bf16(af, bf_, accf, 0, 0, 0);
      accg = __builtin_amdgcn_mfma_f32_16x16x32_bf16(af, bg_, accg, 0, 0, 0);
    }
    if (quad == 0) {
      float bfv = dbf[i * C + co];
      float bgv = dbg[i * C + co];
#pragma unroll
      for (int r = 0; r < 4; ++r) {
        float fv = accf[r] + bfv;
        float gv = accg[r] + bgv;
        float th = 1.f - 2.f / (__expf(2.f * fv) + 1.f);
        float sg = 1.f / (1.f + __expf(-gv));
        Ao[r][co] = f2bf(th * sg);
      }
    }
    __syncthreads();

    f32x4 accr = (f32x4){0.f, 0.f, 0.f, 0.f};
    const u16* wr = tWr + (size_t)(i * C + co) * C;
#pragma unroll
    for (int it = 0; it < 8; ++it) {
      const int kk = it * 32 + kq;
      bf16x8 af = *(const bf16x8*)(&Ao[ncol][kk]);
      bf16x8 br_ = *(const bf16x8*)(wr + kk);
      accr = __builtin_amdgcn_mfma_f32_16x16x32_bf16(af, br_, accr, 0, 0, 0);
    }
    if (quad == 0) {
      float brv = dbr[i * C + co];
#pragma unroll
      for (int r = 0; r < 4; ++r) {
        float hv = h2f[r][co] + accr[r] + brv;
        h2f[r][co] = hv;
        Ah[r][co] = f2bf(hv);
      }
    }
    __syncthreads();
  }

  {
    int b = tid >> 8, c = tid & 255;
    float val = outW[c] * h2f[b][c];
#pragma unroll
    for (int off = 32; off; off >>= 1) val += __shfl_xor(val, off);
    if (lane == 0) atomicAdd(&outred[b], val);
  }
  __syncthreads();
  if (tid < 4) dout[tid] = outred[tid] + outb[0];
}

extern "C" void kernel_launch(void* const* d_in, const int* in_sizes, int n_in,
                              void* d_out, int out_size, void* d_ws, size_t ws_size,
                              hipStream_t stream) {
  const float* x      = (const float*)d_in[0];
  const float* eps    = (const float*)d_in[1];
  const float* encinW = (const float*)d_in[2];
  const float* encinb = (const float*)d_in[3];
  const float* encWf  = (const float*)d_in[4];
  const float* encbf  = (const float*)d_in[5];
  const float* encWg  = (const float*)d_in[6];
  const float* encbg  = (const float*)d_in[7];
  const float* encWr  = (const float*)d_in[8];
  const float* encbr  = (const float*)d_in[9];
  const float* encWs  = (const float*)d_in[10];
  const float* encbs  = (const float*)d_in[11];
  const float* muW    = (const float*)d_in[12];
  const float* mub    = (const float*)d_in[13];
  const float* lvW    = (const float*)d_in[14];
  const float* lvb    = (const float*)d_in[15];
  const float* dinW   = (const float*)d_in[16];
  const float* dinb   = (const float*)d_in[17];
  const float* dWf    = (const float*)d_in[18];
  const float* dbf    = (const float*)d_in[19];
  const float* dWg    = (const float*)d_in[20];
  const float* dbg    = (const float*)d_in[21];
  const float* dWr    = (const float*)d_in[22];
  const float* dbr    = (const float*)d_in[23];
  const float* outW   = (const float*)d_in[24];
  const float* outb   = (const float*)d_in[25];
  float* dout = (float*)d_out;

  const int nFG = NENC * C * C * 2;
  const int nRS = NENC * C * C;
  const int nTD = NDEC * C * C;

  char* ws = (char*)d_ws;
  float* hA = (float*)ws;
  float* hB = hA + (size_t)B * C * T;
  float* pooled = hB + (size_t)B * C * T;
  float* mlbuf = pooled + B * C;
  u16* wWf = (u16*)(mlbuf + 1024);
  u16* wWg = wWf + (size_t)nFG;
  u16* wWr = wWg + (size_t)nFG;
  u16* wWs = wWr + (size_t)nRS;
  u16* tWf = wWs + (size_t)nRS;
  u16* tWg = tWf + (size_t)nTD;
  u16* tWr = tWg + (size_t)nTD;
  u16* tdin = tWr + (size_t)nTD;

  static int attr_set = 0;
  (void)hipFuncSetAttribute(reinterpret_cast<const void*>(k_enc),
                            hipFuncAttributeMaxDynamicSharedMemorySize, 131072);
  (void)attr_set;

  k_cvt<<<(nFG + 255) / 256, 256, 0, stream>>>(encWf, wWf, nFG);
  k_cvt<<<(nFG + 255) / 256, 256, 0, stream>>>(encWg, wWg, nFG);
  k_cvt<<<(nRS + 255) / 256, 256, 0, stream>>>(encWr, wWr, nRS);
  k_cvt<<<(nRS + 255) / 256, 256, 0, stream>>>(encWs, wWs, nRS);
  k_tdec<<<(nTD + 255) / 256, 256, 0, stream>>>(dWf, dWg, dWr, dinW, tWf, tWg, tWr, tdin);

  k_zero<<<4, 256, 0, stream>>>(pooled);
  k_input<<<(B * C * T) / 256, 256, 0, stream>>>(x, encinW, encinb, hA);

  for (int i = 0; i < NENC; ++i) {
    const int dil = 1 << (i % 10);
    const float* hi = (i & 1) ? hB : hA;
    float* ho = (i & 1) ? hA : hB;
    k_enc<<<256, 512, 131072, stream>>>(
        hi, ho, pooled,
        wWf + (size_t)i * C * C * 2, encbf + (size_t)i * C,
        wWg + (size_t)i * C * C * 2, encbg + (size_t)i * C,
        wWr + (size_t)i * C * C,     encbr + (size_t)i * C,
        wWs + (size_t)i * C * C,     encbs + (size_t)i * C,
        dil);
  }

  k_fc<<<16, 256, 0, stream>>>(pooled, muW, mub, lvW, lvb, mlbuf, dout);
  k_dec<<<1, 1024, 0, stream>>>(mlbuf, eps, tdin, dinb, tWf, dbf, tWg, dbg,
                                tWr, dbr, outW, outb, dout);
}